// Round 11
// baseline (2250.831 us; speedup 1.0000x reference)
//
#include <hip/hip_runtime.h>
#include <hip/hip_bf16.h>
#include <math.h>

typedef __hip_bfloat16 bf16;
typedef unsigned short ushort_t;
typedef unsigned int uint_t;

using bf16x8 = __attribute__((ext_vector_type(8))) __bf16;
using f32x4  = __attribute__((ext_vector_type(4))) float;

constexpr int kN  = 64000;
constexpr int kE  = 256000;
constexpr int kG  = 2000;
constexpr int kD  = 300;
constexpr int kH  = 4;
constexpr int kC  = 75;
constexpr int kL  = 5;
constexpr int kED = 32;
constexpr int kFD = 256;
constexpr int kT  = 15;
constexpr int kDp = 320;     // kD padded to multiple of 32 (guard-free DMA staging)
constexpr int kKp2 = 1216;   // 1200 padded to multiple of 32 (mid row stride)
constexpr int kQV = 1280;    // fused q|k|v|skip|qe row stride (1264 used; 2560B = 256B-aligned rows)
constexpr int kQVn = 1264;   // q 0-299 | k 300-599 | v 600-899 | skip 900-1199 | qe 1200-1263
constexpr int kOffK = 300, kOffV = 600, kOffS = 900, kOffQE = 1200;
constexpr int kNpW1 = 1280, kNpW2 = 384;   // B row paddings
constexpr int kW2ld = 1280;  // w2T row stride (1200 used + zero pad)

static inline int cdiv(int a, int b) { return (a + b - 1) / b; }

__device__ __forceinline__ ushort_t f2bf(float f) {
    uint_t u = __float_as_uint(f);
    uint_t r = u + 0x7FFFu + ((u >> 16) & 1u);   // RNE
    return (ushort_t)(r >> 16);
}
__device__ __forceinline__ float bu2f(ushort_t u) {
    return __uint_as_float(((uint_t)u) << 16);
}

__device__ __forceinline__ void gld_lds16(const ushort_t* g, ushort_t* l)
{
    __builtin_amdgcn_global_load_lds(
        (const __attribute__((address_space(1))) void*)g,
        (__attribute__((address_space(3))) void*)(uint_t)(unsigned long long)l,
        16, 0, 0);
}

__global__ void detect_kernel(const uint_t* __restrict__ w, int* __restrict__ flag)
{
    if (threadIdx.x == 0 && blockIdx.x == 0)
        *flag = (w[0] == 0x3F803F80u) ? 1 : 0;
}

// all 23 small-tensor conversions in one launch (dests contiguous in ws)
struct CvtTab {
    const void* src[23];
    long long   off[24];   // cumulative element offsets; off[23] = total
};

__global__ void cvtall_kernel(CvtTab tab, float* __restrict__ base,
                              long long total, const int* __restrict__ flag)
{
    long long i = (long long)blockIdx.x * 256 + threadIdx.x;
    if (i >= total) return;
    int j = 0;
    while (i >= tab.off[j + 1]) j++;
    long long k = i - tab.off[j];
    if (*flag) base[i] = bu2f(((const ushort_t*)tab.src[j])[k]);
    else       base[i] = ((const float*)tab.src[j])[k];
}

__global__ void out_write_kernel(const float* __restrict__ in, void* __restrict__ out,
                                 long long n, long long eoff, const int* __restrict__ flag)
{
    long long i = (long long)blockIdx.x * 256 + threadIdx.x;
    if (i >= n) return;
    if (*flag) ((bf16*)out)[eoff + i] = __float2bfloat16(in[i]);
    else       ((float*)out)[eoff + i] = in[i];
}

// weight transpose, all kL layers in one launch:
// dst[l*layerStride + (rowBase+n)*ldk + k] = W[l*K*N + k*N + n]
__global__ void wtall_kernel(const void* __restrict__ W, ushort_t* __restrict__ WT,
                             int K, int N, int ldk, int rowBase, long long layerStride,
                             const int* __restrict__ flag)
{
    long long i = (long long)blockIdx.x * 256 + threadIdx.x;
    long long per = (long long)K * N;
    if (i >= (long long)kL * per) return;
    int l = (int)(i / per);
    long long r = i - (long long)l * per;
    int k = (int)(r / N), n = (int)(r % N);
    ushort_t val;
    if (*flag) val = ((const ushort_t*)W)[i];
    else       val = f2bf(((const float*)W)[i]);
    WT[(size_t)l * layerStride + (size_t)(rowBase + n) * ldk + k] = val;
}

// bias for QKVS: [q_b | k_b | v_b | skip_b | 0(64) | 0(16)] per layer
__global__ void biasqkvs_kernel(const float* __restrict__ qb, const float* __restrict__ kb,
                                const float* __restrict__ vb, const float* __restrict__ sb,
                                float* __restrict__ out)
{
    int i = blockIdx.x * 256 + threadIdx.x;
    if (i >= kL * kQV) return;
    int l = i / kQV, c = i % kQV;
    float v = 0.f;
    if (c < kOffK)          v = qb[l * kD + c];
    else if (c < kOffV)     v = kb[l * kD + c - kOffK];
    else if (c < kOffS)     v = vb[l * kD + c - kOffV];
    else if (c < kOffQE)    v = sb[l * kD + c - kOffS];
    out[i] = v;
}

// ---------------------------------------------------------------------------
// MFMA bf16 GEMM (round-9 proven form, 2193 µs config): double-buffered async
// staging, XCD-bijective block swizzle, LDS staging swizzle, LDS epilogue
// bounce with coalesced 16B stores. Tile 128x128, BK=32, 256 threads.
// (256x128 tile tried r10: neutral/-0.8% -- K=320 mgemm is launch-shaped.)
// ---------------------------------------------------------------------------
constexpr int gBM = 128, gBN = 128, gBK = 32;
constexpr int kEpiLd = 136;   // epilogue LDS row stride in ushorts (mult of 8)

__global__ __launch_bounds__(256) void mgemm_kernel(
    const ushort_t* __restrict__ A, int lda,
    const ushort_t* __restrict__ BT, int ldb,
    const float* __restrict__ bias,
    ushort_t* __restrict__ outB, int ldob,
    int M, int N, int K, int relu)
{
    __shared__ ushort_t smem[gBM * kEpiLd];   // 34816 B: staging (32KB) then C-bounce
    ushort_t* As = smem;            // [2][128*32] flat
    ushort_t* Bs = smem + 8192;

    const int tid  = threadIdx.x;

    // XCD-aware bijective swizzle of flattened block id
    const int nxg = gridDim.x;
    int bid;
    {
        int nb = nxg * gridDim.y;
        int orig = blockIdx.y * nxg + blockIdx.x;
        int q8 = nb >> 3, r8 = nb & 7;
        int xcd = orig & 7, lid = orig >> 3;
        bid = (xcd < r8 ? xcd * (q8 + 1) : r8 * (q8 + 1) + (xcd - r8) * q8) + lid;
    }
    const int bm = (bid / nxg) * gBM;
    const int bn = (bid % nxg) * gBN;

    const int wave = tid >> 6, lane = tid & 63;
    const int wr = wave >> 1, wc = wave & 1;
    const int lq = lane & 15, qd = lane >> 4;
    // swizzled k-slot for ds_read (matches pre-swizzled global source)
    const int qs = (qd ^ ((lq >> 1) & 3)) * 8;

    f32x4 acc[4][4];
#pragma unroll
    for (int i = 0; i < 4; i++)
#pragma unroll
        for (int j = 0; j < 4; j++) acc[i][j] = (f32x4){0.f, 0.f, 0.f, 0.f};

    // prologue: stage tile 0 into buffer 0 (global k-slot pre-swizzled)
    {
#pragma unroll
        for (int p = 0; p < 2; p++) {
            int u = tid + p * 256;
            gld_lds16(A + (size_t)(bm + (u >> 2)) * lda + ((u ^ (u >> 3)) & 3) * 8, As + u * 8);
        }
#pragma unroll
        for (int p = 0; p < 2; p++) {
            int u = tid + p * 256;
            gld_lds16(BT + (size_t)(bn + (u >> 2)) * ldb + ((u ^ (u >> 3)) & 3) * 8, Bs + u * 8);
        }
    }
    __syncthreads();

    const int nk = K / gBK;
    for (int kt = 0; kt < nk; kt++) {
        const int cb = (kt & 1) * 4096;

        // 1) read fragments of current tile (producers already drained)
        bf16x8 af[4], bfg[4];
#pragma unroll
        for (int i = 0; i < 4; i++)
            af[i] = *reinterpret_cast<const bf16x8*>(&As[cb + (wr * 64 + i * 16 + lq) * gBK + qs]);
#pragma unroll
        for (int j = 0; j < 4; j++)
            bfg[j] = *reinterpret_cast<const bf16x8*>(&Bs[cb + (wc * 64 + j * 16 + lq) * gBK + qs]);

        // 2) issue DMAs for next tile into the other buffer (overlaps MFMA)
        if (kt + 1 < nk) {
            const int k0 = (kt + 1) * gBK;
            const int nb2 = cb ^ 4096;
#pragma unroll
            for (int p = 0; p < 2; p++) {
                int u = tid + p * 256;
                gld_lds16(A + (size_t)(bm + (u >> 2)) * lda + k0 + ((u ^ (u >> 3)) & 3) * 8,
                          As + nb2 + u * 8);
            }
#pragma unroll
            for (int p = 0; p < 2; p++) {
                int u = tid + p * 256;
                gld_lds16(BT + (size_t)(bn + (u >> 2)) * ldb + k0 + ((u ^ (u >> 3)) & 3) * 8,
                          Bs + nb2 + u * 8);
            }
        }

        // 3) MFMA chain
#pragma unroll
        for (int i = 0; i < 4; i++)
#pragma unroll
            for (int j = 0; j < 4; j++)
                acc[i][j] = __builtin_amdgcn_mfma_f32_16x16x32_bf16(af[i], bfg[j], acc[i][j], 0, 0, 0);

        // 4) barrier: drains next-tile DMAs + guards buf reuse
        __syncthreads();
    }

    // epilogue: C/D layout col=lane&15, row=(lane>>4)*4+reg.
#pragma unroll
    for (int i = 0; i < 4; i++) {
#pragma unroll
        for (int j = 0; j < 4; j++) {
            int lcol = wc * 64 + j * 16 + lq;
            int gcol = bn + lcol;
            float bv = (bias && gcol < N) ? bias[gcol] : 0.f;
#pragma unroll
            for (int r2 = 0; r2 < 4; r2++) {
                int lrow = wr * 64 + i * 16 + qd * 4 + r2;
                float v = acc[i][j][r2] + bv;
                if (relu) v = fmaxf(v, 0.f);
                smem[lrow * kEpiLd + lcol] = f2bf(v);
            }
        }
    }
    __syncthreads();
#pragma unroll
    for (int s = 0; s < 8; s++) {
        int seg  = tid + s * 256;
        int lrow = seg >> 4;
        int loff = (seg & 15) * 8;
        int gcol = bn + loff;
        if (gcol + 8 <= ldob) {
            bf16x8 pv = *reinterpret_cast<const bf16x8*>(&smem[lrow * kEpiLd + loff]);
            *reinterpret_cast<bf16x8*>(&outB[(size_t)(bm + lrow) * ldob + gcol]) = pv;
        }
    }
}

// ---------------------------------------------------------------------------
// Fused FFN2 + LN2 (round-7 proven: -20 µs/layer): hb = LN(hb + mid@W2T + b2).
// One block = 128 rows x full N=320 so LN runs in-kernel; f never hits HBM.
// ---------------------------------------------------------------------------
__global__ __launch_bounds__(512, 4) void ffn2ln_kernel(
    const ushort_t* __restrict__ A,      // mid [kN][kKp2], cols 1200-1215 zero
    const ushort_t* __restrict__ BT,     // w2T [384][kW2ld], rows>=300 & cols>=1200 zero
    const float* __restrict__ b2,        // [300]
    ushort_t* hb,                        // [kN][kDp] residual in / LN out
    const float* __restrict__ g, const float* __restrict__ b)
{
    __shared__ ushort_t smem[28672];     // 56KB: As[2][4096] | Bs[2][10240]
    ushort_t* As = smem;
    ushort_t* Bs = smem + 8192;

    // XCD-aware bijective swizzle (1-D grid of 500)
    int bid;
    {
        int nb = gridDim.x, orig = blockIdx.x;
        int q8 = nb >> 3, r8 = nb & 7;
        int xcd = orig & 7, lid = orig >> 3;
        bid = (xcd < r8 ? xcd * (q8 + 1) : r8 * (q8 + 1) + (xcd - r8) * q8) + lid;
    }
    const int bm = bid * 128;

    const int tid  = threadIdx.x;
    const int wave = tid >> 6, lane = tid & 63;
    const int wr = wave >> 1, wc = wave & 1;   // 4 row-groups x 2 col-groups
    const int lq = lane & 15, qd = lane >> 4;
    const int qs = (qd ^ ((lq >> 1) & 3)) * 8;

    auto stage = [&](int kt, int buf) {
        const int k0 = kt * 32;
        {   // A-tile 128x32: 512 16B units, 1 per thread
            int u = tid;
            gld_lds16(A + (size_t)(bm + (u >> 2)) * kKp2 + k0 + ((u ^ (u >> 3)) & 3) * 8,
                      As + buf * 4096 + u * 8);
        }
#pragma unroll
        for (int p = 0; p < 3; p++) {   // B-tile 320x32: 1280 units
            int u = tid + p * 512;
            if (u < 1280)
                gld_lds16(BT + (size_t)(u >> 2) * kW2ld + k0 + ((u ^ (u >> 3)) & 3) * 8,
                          Bs + buf * 10240 + u * 8);
        }
    };

    f32x4 acc[2][10];
#pragma unroll
    for (int i = 0; i < 2; i++)
#pragma unroll
        for (int f = 0; f < 10; f++) acc[i][f] = (f32x4){0.f, 0.f, 0.f, 0.f};

    stage(0, 0);
    __syncthreads();

    for (int kt = 0; kt < kKp2 / 32; kt++) {
        const int cur = kt & 1;
        bf16x8 af0 = *reinterpret_cast<const bf16x8*>(
            &As[cur * 4096 + (wr * 32 + lq) * 32 + qs]);
        bf16x8 af1 = *reinterpret_cast<const bf16x8*>(
            &As[cur * 4096 + (wr * 32 + 16 + lq) * 32 + qs]);
        if (kt + 1 < kKp2 / 32) stage(kt + 1, cur ^ 1);
#pragma unroll
        for (int f = 0; f < 10; f++) {
            bf16x8 bfg = *reinterpret_cast<const bf16x8*>(
                &Bs[cur * 10240 + (wc * 160 + f * 16 + lq) * 32 + qs]);
            acc[0][f] = __builtin_amdgcn_mfma_f32_16x16x32_bf16(af0, bfg, acc[0][f], 0, 0, 0);
            acc[1][f] = __builtin_amdgcn_mfma_f32_16x16x32_bf16(af1, bfg, acc[1][f], 0, 0, 0);
        }
        __syncthreads();   // drains next-tile DMAs + guards buf reuse
    }

    // ---- fused LN2 epilogue: two 64-row halves through LDS (stride 328) ----
    float bv[10];
#pragma unroll
    for (int f = 0; f < 10; f++) {
        int col = wc * 160 + f * 16 + lq;
        bv[f] = (col < kD) ? b2[col] : 0.f;
    }
    const int team = tid >> 6;
#pragma unroll
    for (int h = 0; h < 2; h++) {
        if ((wr >> 1) == h) {
#pragma unroll
            for (int i = 0; i < 2; i++)
#pragma unroll
                for (int f = 0; f < 10; f++)
#pragma unroll
                    for (int r2 = 0; r2 < 4; r2++) {
                        int row = (wr & 1) * 32 + i * 16 + qd * 4 + r2;
                        int col = wc * 160 + f * 16 + lq;
                        smem[row * 328 + col] = f2bf(acc[i][f][r2] + bv[f]);
                    }
        }
        __syncthreads();
        for (int r = 0; r < 8; r++) {
            int rl = team * 8 + r;
            int n = bm + h * 64 + rl;
            size_t baseH = (size_t)n * kDp;
            float vals[5];
            float sum = 0.f;
#pragma unroll
            for (int i5 = 0; i5 < 5; i5++) {
                int idx = lane + i5 * 64;
                float t = 0.f;
                if (idx < kD) t = bu2f(hb[baseH + idx]) + bu2f(smem[rl * 328 + idx]);
                vals[i5] = t;
                sum += t;
            }
            for (int off2 = 1; off2 < 64; off2 <<= 1) sum += __shfl_xor(sum, off2, 64);
            float mean = sum / kD;
            float var = 0.f;
#pragma unroll
            for (int i5 = 0; i5 < 5; i5++) {
                int idx = lane + i5 * 64;
                if (idx < kD) { float dv = vals[i5] - mean; var += dv * dv; }
            }
            for (int off2 = 1; off2 < 64; off2 <<= 1) var += __shfl_xor(var, off2, 64);
            float rstd = rsqrtf(var / kD + 1e-5f);
#pragma unroll
            for (int i5 = 0; i5 < 5; i5++) {
                int idx = lane + i5 * 64;
                if (idx < kD)
                    hb[baseH + idx] = f2bf((vals[i5] - mean) * rstd * g[idx] + b[idx]);
            }
        }
        __syncthreads();
    }
}

// fp32 vector GEMM for the small head matmuls (M=2000)
__global__ __launch_bounds__(256) void gemm_kernel(
    const float* __restrict__ A, const float* __restrict__ W,
    const float* __restrict__ bias, float* __restrict__ C,
    int M, int N, int K, int relu)
{
    constexpr int BM = 64, BN = 64, BK = 16;
    __shared__ float As[BK][BM + 1];
    __shared__ float Bs[BK][BN + 1];
    const int bm = blockIdx.y * BM;
    const int bn = blockIdx.x * BN;
    const int tid = threadIdx.x;
    const int tr = tid / 16;
    const int tc = tid % 16;
    float acc[4][4] = {};
    for (int k0 = 0; k0 < K; k0 += BK) {
        for (int t = tid; t < BM * BK; t += 256) {
            int r = t / BK, c = t % BK;
            int gr = bm + r, gc = k0 + c;
            As[c][r] = (gr < M && gc < K) ? A[(size_t)gr * K + gc] : 0.f;
        }
        for (int t = tid; t < BK * BN; t += 256) {
            int r = t / BN, c = t % BN;
            int gr = k0 + r, gc = bn + c;
            Bs[r][c] = (gr < K && gc < N) ? W[(size_t)gr * N + gc] : 0.f;
        }
        __syncthreads();
#pragma unroll
        for (int k = 0; k < BK; k++) {
            float a[4], b[4];
#pragma unroll
            for (int i = 0; i < 4; i++) a[i] = As[k][tr * 4 + i];
#pragma unroll
            for (int j = 0; j < 4; j++) b[j] = Bs[k][tc * 4 + j];
#pragma unroll
            for (int i = 0; i < 4; i++)
#pragma unroll
                for (int j = 0; j < 4; j++) acc[i][j] += a[i] * b[j];
        }
        __syncthreads();
    }
#pragma unroll
    for (int i = 0; i < 4; i++) {
        int gr = bm + tr * 4 + i;
        if (gr >= M) continue;
#pragma unroll
        for (int j = 0; j < 4; j++) {
            int gc = bn + tc * 4 + j;
            if (gc >= N) continue;
            float v = acc[i][j];
            if (bias) v += bias[gc];
            if (relu) v = fmaxf(v, 0.f);
            C[(size_t)gr * N + gc] = v;
        }
    }
}

// ---------------------------------------------------------------------------
// node embed over full padded rows (pads written 0 -> no separate hb zero)
__global__ void node_embed_kernel(const int* __restrict__ x,
                                  const float* __restrict__ emb1,
                                  const float* __restrict__ emb2,
                                  ushort_t* __restrict__ hb)
{
    long long i = (long long)blockIdx.x * blockDim.x + threadIdx.x;
    if (i >= (long long)kN * kDp) return;
    int n = (int)(i / kDp), d = (int)(i % kDp);
    ushort_t v = 0;
    if (d < kD)
        v = f2bf(emb1[(size_t)x[n * 2] * kD + d] + emb2[(size_t)x[n * 2 + 1] * kD + d]);
    hb[i] = v;
}

__global__ void eftab_kernel(const float* __restrict__ emb_t, const float* __restrict__ emb_d,
                             const float* __restrict__ pw, const float* __restrict__ pb,
                             float* __restrict__ eftab)
{
    int tid = threadIdx.x;
    if (tid >= kT * kED) return;
    int t = tid / kED, j = tid % kED;
    int a0 = t / 3, a1 = t % 3;
    float acc = pb[j];
#pragma unroll
    for (int k = 0; k < kED; k++) {
        float s = emb_t[a0 * kED + k] + emb_d[a1 * kED + k];
        acc += s * pw[k * kED + j];
    }
    eftab[tid] = acc;
}

// all kL layers in one launch: blockIdx.x = layer
__global__ __launch_bounds__(256) void etaball_kernel(const float* __restrict__ eftab,
                                                      const float* __restrict__ ew5,
                                                      float* __restrict__ etab5)
{
    __shared__ float se[kT * kED];
    const int l = blockIdx.x;
    const float* ew = ew5 + (size_t)l * kED * kD;
    float* etab = etab5 + (size_t)l * kT * kD;
    for (int i = threadIdx.x; i < kT * kED; i += 256) se[i] = eftab[i];
    __syncthreads();
    for (int o = threadIdx.x; o < kT * kD; o += 256) {
        int t = o / kD, d = o % kD;
        float acc = 0.f;
#pragma unroll
        for (int k = 0; k < kED; k++) acc += se[t * kED + k] * ew[k * kD + d];
        etab[o] = acc;
    }
}

// EtabT2 rows for all layers: row j=t*4+h is etab[t] masked to head h.
__global__ void etabT2all_kernel(const float* __restrict__ etab5, ushort_t* __restrict__ wqv5)
{
    int i = blockIdx.x * 256 + threadIdx.x;
    if (i >= kL * 64 * kDp) return;
    int l = i / (64 * kDp);
    int r = i - l * (64 * kDp);
    int j = r / kDp, k = r % kDp;
    const float* etab = etab5 + (size_t)l * kT * kD;
    ushort_t v = 0;
    if (j < kT * kH && k < kD) {
        int t = j >> 2, hh = j & 3;
        if (k >= hh * kC && k < hh * kC + kC) v = f2bf(etab[t * kD + k]);
    }
    wqv5[(size_t)l * kQV * kDp + (size_t)kOffQE * kDp + r] = v;
}

// ---------------- CSR build (by dst) ----------------
__global__ void izero_kernel(int* __restrict__ p, int n)
{
    int i = blockIdx.x * 256 + threadIdx.x;
    if (i < n) p[i] = 0;
}

__global__ void deg_kernel(const int* __restrict__ dst, int* __restrict__ deg)
{
    int e = blockIdx.x * 256 + threadIdx.x;
    if (e >= kE) return;
    atomicAdd(&deg[dst[e]], 1);
}

__global__ __launch_bounds__(256) void scan1_kernel(const int* __restrict__ deg, int* __restrict__ bsum)
{
    __shared__ int s[256];
    int i = blockIdx.x * 256 + threadIdx.x;
    s[threadIdx.x] = (i < kN) ? deg[i] : 0;
    __syncthreads();
    for (int off = 128; off > 0; off >>= 1) {
        if (threadIdx.x < off) s[threadIdx.x] += s[threadIdx.x + off];
        __syncthreads();
    }
    if (threadIdx.x == 0) bsum[blockIdx.x] = s[0];
}

__global__ __launch_bounds__(256) void scan2_kernel(const int* __restrict__ bsum, int* __restrict__ boff,
                                                    int nb, int* __restrict__ row_ptr)
{
    __shared__ int s[256];
    int tid = threadIdx.x;
    int v = (tid < nb) ? bsum[tid] : 0;
    s[tid] = v;
    __syncthreads();
    for (int off = 1; off < 256; off <<= 1) {
        int t = (tid >= off) ? s[tid - off] : 0;
        __syncthreads();
        s[tid] += t;
        __syncthreads();
    }
    if (tid < nb) boff[tid] = s[tid] - v;
    if (tid == 255) row_ptr[kN] = s[255];
}

__global__ __launch_bounds__(256) void scan3_kernel(const int* __restrict__ deg, const int* __restrict__ boff,
                                                    int* __restrict__ row_ptr)
{
    __shared__ int s[256];
    int tid = threadIdx.x;
    int i = blockIdx.x * 256 + tid;
    int v = (i < kN) ? deg[i] : 0;
    s[tid] = v;
    __syncthreads();
    for (int off = 1; off < 256; off <<= 1) {
        int t = (tid >= off) ? s[tid - off] : 0;
        __syncthreads();
        s[tid] += t;
        __syncthreads();
    }
    if (i < kN) row_ptr[i] = boff[blockIdx.x] + s[tid] - v;
}

__global__ void poscopy_kernel(const int* __restrict__ row_ptr, int* __restrict__ pos)
{
    int i = blockIdx.x * 256 + threadIdx.x;
    if (i < kN) pos[i] = row_ptr[i];
}

__global__ void fill_kernel(const int* __restrict__ src, const int* __restrict__ dst,
                            const int* __restrict__ edge_attr,
                            int* __restrict__ pos, int* __restrict__ cpack)
{
    int e = blockIdx.x * 256 + threadIdx.x;
    if (e >= kE) return;
    int d = dst[e];
    int slot = atomicAdd(&pos[d], 1);
    cpack[slot] = (src[e] << 8) | (edge_attr[e * 2] * 3 + edge_attr[e * 2 + 1]);
}

// graph boundary pointers from sorted batch
__global__ void gptr_kernel(const int* __restrict__ batch, int* __restrict__ gptr)
{
    int i = blockIdx.x * 256 + threadIdx.x;
    if (i >= kN) return;
    int b1 = batch[i];
    int b0 = (i == 0) ? -1 : batch[i - 1];
    for (int g = b0 + 1; g <= b1; g++) gptr[g] = i;
    if (i == kN - 1)
        for (int g = b1 + 1; g <= kG; g++) gptr[g] = kN;
}

// ---------------------------------------------------------------------------
// Fused gather+score+LN1. Round-6 proven form (2-edge unroll) + this round:
// V-gather loads hoisted to issue alongside K-gather loads (20 loads in
// flight per edge-pair instead of 10; numerically identical expression).
// ---------------------------------------------------------------------------
__global__ __launch_bounds__(256) void gsln_kernel(
    const int* __restrict__ row_ptr, const int* __restrict__ cpack,
    const ushort_t* __restrict__ qkvs,
    const float* __restrict__ etab,
    const float* __restrict__ g, const float* __restrict__ b,
    ushort_t* __restrict__ hb)
{
    __shared__ float sE[kT * kD];
    for (int i = threadIdx.x; i < kT * kD; i += 256) sE[i] = etab[i];
    __syncthreads();
    const int wslot = threadIdx.x >> 6, lane = threadIdx.x & 63;
    const int hh = lane >> 4, sub = lane & 15;
    const float scale = 0.11547005383792516f;

    int idxj[5];
    bool vj[5];
#pragma unroll
    for (int j = 0; j < 5; j++) {
        int o = sub + 16 * j;
        vj[j] = (o < kC);
        idxj[j] = hh * kC + (vj[j] ? o : 0);
    }

    for (int it = 0; it < 4; it++) {
        int n = blockIdx.x * 4 + wslot + it * 16000;
        int beg = row_ptr[n], end = row_ptr[n + 1];
        const ushort_t* qrow = qkvs + (size_t)n * kQV;

        float qv[5];
#pragma unroll
        for (int j = 0; j < 5; j++)
            qv[j] = vj[j] ? bu2f(qrow[idxj[j]]) : 0.f;

        float acc[5] = {0.f, 0.f, 0.f, 0.f, 0.f};
        float den = 0.f;
        for (int i = beg; i < end; i += 2) {
            int pk0 = cpack[i];
            bool h1 = (i + 1 < end);
            int pk1 = cpack[h1 ? i + 1 : i];
            int s0 = pk0 >> 8, t0 = pk0 & 255;
            int s1 = pk1 >> 8, t1 = pk1 & 255;
            const ushort_t* sr0 = qkvs + (size_t)s0 * kQV;
            const ushort_t* sr1 = qkvs + (size_t)s1 * kQV;

            // K AND V loads for both edges issued together (max MLP)
            float k0v[5], k1v[5], v0v[5], v1v[5];
#pragma unroll
            for (int j = 0; j < 5; j++) {
                k0v[j] = vj[j] ? bu2f(sr0[kOffK + idxj[j]]) : 0.f;
                k1v[j] = vj[j] ? bu2f(sr1[kOffK + idxj[j]]) : 0.f;
            }
#pragma unroll
            for (int j = 0; j < 5; j++) {
                v0v[j] = vj[j] ? bu2f(sr0[kOffV + idxj[j]]) : 0.f;
                v1v[j] = vj[j] ? bu2f(sr1[kOffV + idxj[j]]) : 0.f;
            }
            float qe0 = bu2f(qrow[kOffQE + t0 * kH + hh]);
            float qe1 = bu2f(qrow[kOffQE + t1 * kH + hh]);

            float hp0 = 0.f, hp1 = 0.f;
#pragma unroll
            for (int j = 0; j < 5; j++) {
                hp0 += qv[j] * k0v[j];
                hp1 += qv[j] * k1v[j];
            }
            hp0 += __shfl_xor(hp0, 1, 64);  hp1 += __shfl_xor(hp1, 1, 64);
            hp0 += __shfl_xor(hp0, 2, 64);  hp1 += __shfl_xor(hp1, 2, 64);
            hp0 += __shfl_xor(hp0, 4, 64);  hp1 += __shfl_xor(hp1, 4, 64);
            hp0 += __shfl_xor(hp0, 8, 64);  hp1 += __shfl_xor(hp1, 8, 64);
            float a0 = fminf(fmaxf((hp0 + qe0) * scale, -60.f), 60.f);
            float a1 = fminf(fmaxf((hp1 + qe1) * scale, -60.f), 60.f);
            float eh0 = __expf(a0);
            float eh1 = h1 ? __expf(a1) : 0.f;
            den += eh0 + eh1;

            const float* ep0 = sE + t0 * kD;
            const float* ep1 = sE + t1 * kD;
#pragma unroll
            for (int j = 0; j < 5; j++) {
                if (vj[j]) {
                    acc[j] += eh0 * (v0v[j] + ep0[idxj[j]])
                            + eh1 * (v1v[j] + ep1[idxj[j]]);
                }
            }
        }

        const float inv_den = (den > 0.f) ? 1.f / den : 0.f;
        const ushort_t* skipp = qrow + kOffS;
        float vals[5], sum = 0.f;
#pragma unroll
        for (int j = 0; j < 5; j++) {
            float tV = 0.f;
            if (vj[j])
                tV = bu2f(hb[(size_t)n * kDp + idxj[j]]) + acc[j] * inv_den + bu2f(skipp[idxj[j]]);
            vals[j] = tV;
            sum += tV;
        }
        for (int off = 1; off < 64; off <<= 1) sum += __shfl_xor(sum, off, 64);
        float mean = sum / kD;
        float var = 0.f;
#pragma unroll
        for (int j = 0; j < 5; j++) {
            if (vj[j]) { float dv = vals[j] - mean; var += dv * dv; }
        }
        for (int off = 1; off < 64; off <<= 1) var += __shfl_xor(var, off, 64);
        float rstd = rsqrtf(var / kD + 1e-5f);
#pragma unroll
        for (int j = 0; j < 5; j++) {
            if (vj[j])
                hb[(size_t)n * kDp + idxj[j]] =
                    f2bf((vals[j] - mean) * rstd * g[idxj[j]] + b[idxj[j]]);
        }
    }
}

__global__ void zero_kernel(float* __restrict__ p, long long n)
{
    long long i = (long long)blockIdx.x * blockDim.x + threadIdx.x;
    if (i < n) p[i] = 0.f;
}

// mean-pool per graph (sorted batch -> segmented reduction, no atomics)
__global__ __launch_bounds__(256) void pool2_kernel(const ushort_t* __restrict__ hb,
                                                    const int* __restrict__ gptr,
                                                    float* __restrict__ pooled)
{
    int g = blockIdx.x;
    int beg = gptr[g], end = gptr[g + 1];
    float inv = (end > beg) ? 1.f / (float)(end - beg) : 0.f;
    for (int d = threadIdx.x; d < kD; d += 256) {
        float acc = 0.f;
        for (int n = beg; n < end; n++)
            acc += bu2f(hb[(size_t)n * kDp + d]);
        pooled[(size_t)g * kD + d] = acc * inv;
    }
}

// ---------------------------------------------------------------------------
extern "C" void kernel_launch(void* const* d_in, const int* in_sizes, int n_in,
                              void* d_out, int out_size, void* d_ws, size_t ws_size,
                              hipStream_t stream)
{
    const int* x          = (const int*)d_in[0];
    const int* edge_index = (const int*)d_in[1];
    const int* edge_attr  = (const int*)d_in[2];
    const int* batch      = (const int*)d_in[3];
    const int* src = edge_index;
    const int* dst = edge_index + kE;

    // ---- workspace layout (~221 MB; proven budget >= 266.8 MB) ----
    float* ws = (float*)d_ws;
    size_t off = 0;
    int* flag = (int*)(ws + off); off += 16;
    const bool big[33] = {false,false,false,false,false,false,false,false,false,false,
                          true, false, true, false, true, false, false, true, false, false,
                          false,false,false, true, false, true, false,false,false,false,
                          false,false,false};
    float* canonBase = ws + off;
    float* canon[33] = {};
    CvtTab tab;
    {
        int cnt = 0;
        long long cum = 0;
        for (int i = 4; i < 33; i++) {
            if (big[i]) continue;
            canon[i] = ws + off; off += (size_t)in_sizes[i];
            tab.src[cnt] = d_in[i];
            tab.off[cnt] = cum;
            cum += in_sizes[i];
            cnt++;
        }
        tab.off[cnt] = cum;   // cnt == 23
    }
    const long long cvtTotal = tab.off[23];
    off = (off + 3) & ~(size_t)3;
    int* deg     = (int*)(ws + off); off += (size_t)kN;
    int* row_ptr = (int*)(ws + off); off += (size_t)kN + 4;
    int* pos     = (int*)(ws + off); off += (size_t)kN;
    int* cpack   = (int*)(ws + off); off += (size_t)kE;
    int* bsum    = (int*)(ws + off); off += 256;
    int* boff    = (int*)(ws + off); off += 256;
    int* gptr    = (int*)(ws + off); off += (size_t)kG + 4;
    float* eftab = ws + off; off += (size_t)kT * kED;
    float* etab5 = ws + off; off += (size_t)kL * kT * kD;
    float* bqv5  = ws + off; off += (size_t)kL * kQV;
    off = (off + 3) & ~(size_t)3;
    ushort_t* hb   = (ushort_t*)(ws + off); off += (size_t)kN * kDp / 2;   // 41 MB
    ushort_t* QV   = (ushort_t*)(ws + off); off += (size_t)kN * kQV / 2;   // 164 MB (QKVS / FFN-mid)
    // per-layer transposed bf16 weights (arena pre-zeroed)
    ushort_t* warena = (ushort_t*)(ws + off);
    ushort_t* wqv5 = warena;                              // [kL][kQV][kDp]
    ushort_t* wt15 = wqv5 + (size_t)kL * kQV * kDp;       // [kL][kNpW1][kDp]
    ushort_t* wt25 = wt15 + (size_t)kL * kNpW1 * kDp;     // [kL][kNpW2][kW2ld]
    size_t warena_ushorts = (size_t)kL * (kQV + kNpW1) * kDp + (size_t)kL * kNpW2 * kW2ld;
    off += warena_ushorts / 2 + 4;
    // head temporaries alias QV (free after layer loop)
    float* pooled = (float*)QV;
    float* gbuf   = pooled + (size_t)kG * kD;
    float* t1     = gbuf + (size_t)kG * kFD;
    float* o2     = t1 + (size_t)kG * kFD;

    // ---- dtype detect + canonicalize all small tensors in ONE launch ----
    detect_kernel<<<1, 64, 0, stream>>>((const uint_t*)d_in[19], flag);
    cvtall_kernel<<<cdiv((int)cvtTotal, 256), 256, 0, stream>>>(tab, canonBase, cvtTotal, flag);

    auto mgemm = [&](const ushort_t* A, int lda, const ushort_t* BT, int ldb,
                     const float* bias, ushort_t* outB, int ldob,
                     int M, int N, int K, int relu) {
        dim3 grid(cdiv(N, gBN), M / gBM);
        mgemm_kernel<<<grid, 256, 0, stream>>>(A, lda, BT, ldb, bias, outB, ldob, M, N, K, relu);
    };
    auto gemm = [&](const float* A, const float* W, const float* bias, float* C,
                    int M, int N, int K, int relu) {
        dim3 grid(cdiv(N, 64), cdiv(M, 64));
        gemm_kernel<<<grid, 256, 0, stream>>>(A, W, bias, C, M, N, K, relu);
    };

    // ---- embeddings (full padded rows -> no separate hb zero) ----
    node_embed_kernel<<<cdiv((int)((long long)kN * kDp), 256), 256, 0, stream>>>(
        x, canon[4], canon[5], hb);
    eftab_kernel<<<1, 512, 0, stream>>>(canon[6], canon[7], canon[8], canon[9], eftab);

    // ---- CSR build + graph boundaries (once) ----
    const int nb = cdiv(kN, 256);   // 250
    izero_kernel<<<cdiv(kN, 256), 256, 0, stream>>>(deg, kN);
    deg_kernel<<<cdiv(kE, 256), 256, 0, stream>>>(dst, deg);
    scan1_kernel<<<nb, 256, 0, stream>>>(deg, bsum);
    scan2_kernel<<<1, 256, 0, stream>>>(bsum, boff, nb, row_ptr);
    scan3_kernel<<<nb, 256, 0, stream>>>(deg, boff, row_ptr);
    poscopy_kernel<<<cdiv(kN, 256), 256, 0, stream>>>(row_ptr, pos);
    fill_kernel<<<cdiv(kE, 256), 256, 0, stream>>>(src, dst, edge_attr, pos, cpack);
    gptr_kernel<<<cdiv(kN, 256), 256, 0, stream>>>(batch, gptr);

    // ---- weight prep: zero arena (pads must be 0), then batched fills ----
    zero_kernel<<<cdiv((int)(warena_ushorts / 2), 256) + 1, 256, 0, stream>>>(
        (float*)warena, (long long)(warena_ushorts / 2));
    {
        const long long sQV = (long long)kQV * kDp;
        const int g300 = cdiv(kL * kD * kD, 256);
        wtall_kernel<<<g300, 256, 0, stream>>>(d_in[10], wqv5, kD, kD, kDp, 0,     sQV, flag);
        wtall_kernel<<<g300, 256, 0, stream>>>(d_in[12], wqv5, kD, kD, kDp, kOffK, sQV, flag);
        wtall_kernel<<<g300, 256, 0, stream>>>(d_in[14], wqv5, kD, kD, kDp, kOffV, sQV, flag);
        wtall_kernel<<<g300, 256, 0, stream>>>(d_in[17], wqv5, kD, kD, kDp, kOffS, sQV, flag);
        wtall_kernel<<<cdiv(kL * kD * 1200, 256), 256, 0, stream>>>(
            d_in[23], wt15, kD, 1200, kDp, 0, (long long)kNpW1 * kDp, flag);
        wtall_kernel<<<cdiv(kL * 1200 * kD, 256), 256, 0, stream>>>(
            d_in[25], wt25, 1200, kD, kW2ld, 0, (long long)kNpW2 * kW2ld, flag);
    }
    etaball_kernel<<<kL, 256, 0, stream>>>(eftab, canon[16], etab5);
    etabT2all_kernel<<<cdiv(kL * 64 * kDp, 256), 256, 0, stream>>>(etab5, wqv5);
    biasqkvs_kernel<<<cdiv(kL * kQV, 256), 256, 0, stream>>>(
        canon[11], canon[13], canon[15], canon[18], bqv5);

    // ---- layers ----
    for (int l = 0; l < kL; l++) {
        const ushort_t* wqv = wqv5 + (size_t)l * kQV * kDp;
        const ushort_t* w1  = wt15 + (size_t)l * kNpW1 * kDp;
        const ushort_t* w2  = wt25 + (size_t)l * kNpW2 * kW2ld;
        const float* etab = etab5 + (size_t)l * kT * kD;

        // QKVS = hb @ [q|k|v|skip|qe]  (N=1264, stride 1280)
        mgemm(hb, kDp, wqv, kDp, bqv5 + (size_t)l * kQV, QV, kQV, kN, kQVn, kDp, 0);

        // fused gather+score+LN1 -> hb
        gsln_kernel<<<4000, 256, 0, stream>>>(row_ptr, cpack, QV, etab,
            canon[19] + (size_t)l * kD, canon[20] + (size_t)l * kD, hb);

        // FFN1 (proven mgemm): mid (bf16 [64000][1216]) in QV
        ushort_t* mid = QV;
        mgemm(hb, kDp, w1, kDp, canon[24] + (size_t)l * 1200, mid, kKp2,
              kN, 1200, kDp, 1);

        // fused FFN2+LN2: hb = LN(hb + mid @ w2T + b2); f never hits HBM
        ffn2ln_kernel<<<kN / 128, 512, 0, stream>>>(mid, w2,
            canon[26] + (size_t)l * kD, hb,
            canon[21] + (size_t)l * kD, canon[22] + (size_t)l * kD);
    }

    // ---- pooling + heads (QV free) ----
    pool2_kernel<<<kG, 256, 0, stream>>>(hb, gptr, pooled);

    gemm(pooled, canon[27], canon[28], gbuf, kG, kFD, kD, 0);
    gemm(gbuf, canon[29], canon[30], t1, kG, kFD, kFD, 1);
    gemm(t1, canon[31], canon[32], o2, kG, kFD / 2, kFD, 0);

    out_write_kernel<<<cdiv(kG * kFD, 256), 256, 0, stream>>>(
        gbuf, d_out, (long long)kG * kFD, 0, flag);
    out_write_kernel<<<cdiv(kG * kFD / 2, 256), 256, 0, stream>>>(
        o2, d_out, (long long)kG * (kFD / 2), (long long)kG * kFD, flag);
}

// Round 12
// 2150.545 us; speedup vs baseline: 1.0466x; 1.0466x over previous
//
#include <hip/hip_runtime.h>
#include <hip/hip_bf16.h>
#include <math.h>

typedef __hip_bfloat16 bf16;
typedef unsigned short ushort_t;
typedef unsigned int uint_t;

using bf16x8 = __attribute__((ext_vector_type(8))) __bf16;
using f32x4  = __attribute__((ext_vector_type(4))) float;

constexpr int kN  = 64000;
constexpr int kE  = 256000;
constexpr int kG  = 2000;
constexpr int kD  = 300;
constexpr int kH  = 4;
constexpr int kC  = 75;
constexpr int kL  = 5;
constexpr int kED = 32;
constexpr int kFD = 256;
constexpr int kT  = 15;
constexpr int kDp = 320;     // kD padded to multiple of 32 (guard-free DMA staging)
constexpr int kKp2 = 1216;   // 1200 padded to multiple of 32 (mid row stride)
constexpr int kQV = 1280;    // fused q|k|v|skip|qe row stride (1264 used; 2560B = 256B-aligned rows)
constexpr int kQVn = 1264;   // q 0-299 | k 300-599 | v 600-899 | skip 900-1199 | qe 1200-1263
constexpr int kOffK = 300, kOffV = 600, kOffS = 900, kOffQE = 1200;
constexpr int kNpW1 = 1280, kNpW2 = 384;   // B row paddings
constexpr int kW2ld = 1280;  // w2T row stride (1200 used + zero pad)

static inline int cdiv(int a, int b) { return (a + b - 1) / b; }

__device__ __forceinline__ ushort_t f2bf(float f) {
    uint_t u = __float_as_uint(f);
    uint_t r = u + 0x7FFFu + ((u >> 16) & 1u);   // RNE
    return (ushort_t)(r >> 16);
}
__device__ __forceinline__ float bu2f(ushort_t u) {
    return __uint_as_float(((uint_t)u) << 16);
}

__device__ __forceinline__ void gld_lds16(const ushort_t* g, ushort_t* l)
{
    __builtin_amdgcn_global_load_lds(
        (const __attribute__((address_space(1))) void*)g,
        (__attribute__((address_space(3))) void*)(uint_t)(unsigned long long)l,
        16, 0, 0);
}

__global__ void detect_kernel(const uint_t* __restrict__ w, int* __restrict__ flag)
{
    if (threadIdx.x == 0 && blockIdx.x == 0)
        *flag = (w[0] == 0x3F803F80u) ? 1 : 0;
}

// all 23 small-tensor conversions in one launch (dests contiguous in ws)
struct CvtTab {
    const void* src[23];
    long long   off[24];   // cumulative element offsets; off[23] = total
};

__global__ void cvtall_kernel(CvtTab tab, float* __restrict__ base,
                              long long total, const int* __restrict__ flag)
{
    long long i = (long long)blockIdx.x * 256 + threadIdx.x;
    if (i >= total) return;
    int j = 0;
    while (i >= tab.off[j + 1]) j++;
    long long k = i - tab.off[j];
    if (*flag) base[i] = bu2f(((const ushort_t*)tab.src[j])[k]);
    else       base[i] = ((const float*)tab.src[j])[k];
}

__global__ void out_write_kernel(const float* __restrict__ in, void* __restrict__ out,
                                 long long n, long long eoff, const int* __restrict__ flag)
{
    long long i = (long long)blockIdx.x * 256 + threadIdx.x;
    if (i >= n) return;
    if (*flag) ((bf16*)out)[eoff + i] = __float2bfloat16(in[i]);
    else       ((float*)out)[eoff + i] = in[i];
}

// weight transpose, all kL layers in one launch:
// dst[l*layerStride + (rowBase+n)*ldk + k] = W[l*K*N + k*N + n]
__global__ void wtall_kernel(const void* __restrict__ W, ushort_t* __restrict__ WT,
                             int K, int N, int ldk, int rowBase, long long layerStride,
                             const int* __restrict__ flag)
{
    long long i = (long long)blockIdx.x * 256 + threadIdx.x;
    long long per = (long long)K * N;
    if (i >= (long long)kL * per) return;
    int l = (int)(i / per);
    long long r = i - (long long)l * per;
    int k = (int)(r / N), n = (int)(r % N);
    ushort_t val;
    if (*flag) val = ((const ushort_t*)W)[i];
    else       val = f2bf(((const float*)W)[i]);
    WT[(size_t)l * layerStride + (size_t)(rowBase + n) * ldk + k] = val;
}

// bias for QKVS: [q_b | k_b | v_b | skip_b | 0(64) | 0(16)] per layer
__global__ void biasqkvs_kernel(const float* __restrict__ qb, const float* __restrict__ kb,
                                const float* __restrict__ vb, const float* __restrict__ sb,
                                float* __restrict__ out)
{
    int i = blockIdx.x * 256 + threadIdx.x;
    if (i >= kL * kQV) return;
    int l = i / kQV, c = i % kQV;
    float v = 0.f;
    if (c < kOffK)          v = qb[l * kD + c];
    else if (c < kOffV)     v = kb[l * kD + c - kOffK];
    else if (c < kOffS)     v = vb[l * kD + c - kOffV];
    else if (c < kOffQE)    v = sb[l * kD + c - kOffS];
    out[i] = v;
}

// ---------------------------------------------------------------------------
// MFMA bf16 GEMM (round-9 proven form, 2193 µs config): double-buffered async
// staging, XCD-bijective block swizzle, LDS staging swizzle, LDS epilogue
// bounce with coalesced 16B stores. Tile 128x128, BK=32, 256 threads.
// (256x128 tile tried r10: neutral -- K=320 mgemm is launch-shaped.)
// ---------------------------------------------------------------------------
constexpr int gBM = 128, gBN = 128, gBK = 32;
constexpr int kEpiLd = 136;   // epilogue LDS row stride in ushorts (mult of 8)

__global__ __launch_bounds__(256) void mgemm_kernel(
    const ushort_t* __restrict__ A, int lda,
    const ushort_t* __restrict__ BT, int ldb,
    const float* __restrict__ bias,
    ushort_t* __restrict__ outB, int ldob,
    int M, int N, int K, int relu)
{
    __shared__ ushort_t smem[gBM * kEpiLd];   // 34816 B: staging (32KB) then C-bounce
    ushort_t* As = smem;            // [2][128*32] flat
    ushort_t* Bs = smem + 8192;

    const int tid  = threadIdx.x;

    // XCD-aware bijective swizzle of flattened block id
    const int nxg = gridDim.x;
    int bid;
    {
        int nb = nxg * gridDim.y;
        int orig = blockIdx.y * nxg + blockIdx.x;
        int q8 = nb >> 3, r8 = nb & 7;
        int xcd = orig & 7, lid = orig >> 3;
        bid = (xcd < r8 ? xcd * (q8 + 1) : r8 * (q8 + 1) + (xcd - r8) * q8) + lid;
    }
    const int bm = (bid / nxg) * gBM;
    const int bn = (bid % nxg) * gBN;

    const int wave = tid >> 6, lane = tid & 63;
    const int wr = wave >> 1, wc = wave & 1;
    const int lq = lane & 15, qd = lane >> 4;
    // swizzled k-slot for ds_read (matches pre-swizzled global source)
    const int qs = (qd ^ ((lq >> 1) & 3)) * 8;

    f32x4 acc[4][4];
#pragma unroll
    for (int i = 0; i < 4; i++)
#pragma unroll
        for (int j = 0; j < 4; j++) acc[i][j] = (f32x4){0.f, 0.f, 0.f, 0.f};

    // prologue: stage tile 0 into buffer 0 (global k-slot pre-swizzled)
    {
#pragma unroll
        for (int p = 0; p < 2; p++) {
            int u = tid + p * 256;
            gld_lds16(A + (size_t)(bm + (u >> 2)) * lda + ((u ^ (u >> 3)) & 3) * 8, As + u * 8);
        }
#pragma unroll
        for (int p = 0; p < 2; p++) {
            int u = tid + p * 256;
            gld_lds16(BT + (size_t)(bn + (u >> 2)) * ldb + ((u ^ (u >> 3)) & 3) * 8, Bs + u * 8);
        }
    }
    __syncthreads();

    const int nk = K / gBK;
    for (int kt = 0; kt < nk; kt++) {
        const int cb = (kt & 1) * 4096;

        // 1) read fragments of current tile (producers already drained)
        bf16x8 af[4], bfg[4];
#pragma unroll
        for (int i = 0; i < 4; i++)
            af[i] = *reinterpret_cast<const bf16x8*>(&As[cb + (wr * 64 + i * 16 + lq) * gBK + qs]);
#pragma unroll
        for (int j = 0; j < 4; j++)
            bfg[j] = *reinterpret_cast<const bf16x8*>(&Bs[cb + (wc * 64 + j * 16 + lq) * gBK + qs]);

        // 2) issue DMAs for next tile into the other buffer (overlaps MFMA)
        if (kt + 1 < nk) {
            const int k0 = (kt + 1) * gBK;
            const int nb2 = cb ^ 4096;
#pragma unroll
            for (int p = 0; p < 2; p++) {
                int u = tid + p * 256;
                gld_lds16(A + (size_t)(bm + (u >> 2)) * lda + k0 + ((u ^ (u >> 3)) & 3) * 8,
                          As + nb2 + u * 8);
            }
#pragma unroll
            for (int p = 0; p < 2; p++) {
                int u = tid + p * 256;
                gld_lds16(BT + (size_t)(bn + (u >> 2)) * ldb + k0 + ((u ^ (u >> 3)) & 3) * 8,
                          Bs + nb2 + u * 8);
            }
        }

        // 3) MFMA chain
#pragma unroll
        for (int i = 0; i < 4; i++)
#pragma unroll
            for (int j = 0; j < 4; j++)
                acc[i][j] = __builtin_amdgcn_mfma_f32_16x16x32_bf16(af[i], bfg[j], acc[i][j], 0, 0, 0);

        // 4) barrier: drains next-tile DMAs + guards buf reuse
        __syncthreads();
    }

    // epilogue: C/D layout col=lane&15, row=(lane>>4)*4+reg.
#pragma unroll
    for (int i = 0; i < 4; i++) {
#pragma unroll
        for (int j = 0; j < 4; j++) {
            int lcol = wc * 64 + j * 16 + lq;
            int gcol = bn + lcol;
            float bv = (bias && gcol < N) ? bias[gcol] : 0.f;
#pragma unroll
            for (int r2 = 0; r2 < 4; r2++) {
                int lrow = wr * 64 + i * 16 + qd * 4 + r2;
                float v = acc[i][j][r2] + bv;
                if (relu) v = fmaxf(v, 0.f);
                smem[lrow * kEpiLd + lcol] = f2bf(v);
            }
        }
    }
    __syncthreads();
#pragma unroll
    for (int s = 0; s < 8; s++) {
        int seg  = tid + s * 256;
        int lrow = seg >> 4;
        int loff = (seg & 15) * 8;
        int gcol = bn + loff;
        if (gcol + 8 <= ldob) {
            bf16x8 pv = *reinterpret_cast<const bf16x8*>(&smem[lrow * kEpiLd + loff]);
            *reinterpret_cast<bf16x8*>(&outB[(size_t)(bm + lrow) * ldob + gcol]) = pv;
        }
    }
}

// ---------------------------------------------------------------------------
// Fused FFN2 + LN2 (round-7 proven: -20 µs/layer): hb = LN(hb + mid@W2T + b2).
// One block = 128 rows x full N=320 so LN runs in-kernel; f never hits HBM.
// ---------------------------------------------------------------------------
__global__ __launch_bounds__(512, 4) void ffn2ln_kernel(
    const ushort_t* __restrict__ A,      // mid [kN][kKp2], cols 1200-1215 zero
    const ushort_t* __restrict__ BT,     // w2T [384][kW2ld], rows>=300 & cols>=1200 zero
    const float* __restrict__ b2,        // [300]
    ushort_t* hb,                        // [kN][kDp] residual in / LN out
    const float* __restrict__ g, const float* __restrict__ b)
{
    __shared__ ushort_t smem[28672];     // 56KB: As[2][4096] | Bs[2][10240]
    ushort_t* As = smem;
    ushort_t* Bs = smem + 8192;

    // XCD-aware bijective swizzle (1-D grid of 500)
    int bid;
    {
        int nb = gridDim.x, orig = blockIdx.x;
        int q8 = nb >> 3, r8 = nb & 7;
        int xcd = orig & 7, lid = orig >> 3;
        bid = (xcd < r8 ? xcd * (q8 + 1) : r8 * (q8 + 1) + (xcd - r8) * q8) + lid;
    }
    const int bm = bid * 128;

    const int tid  = threadIdx.x;
    const int wave = tid >> 6, lane = tid & 63;
    const int wr = wave >> 1, wc = wave & 1;   // 4 row-groups x 2 col-groups
    const int lq = lane & 15, qd = lane >> 4;
    const int qs = (qd ^ ((lq >> 1) & 3)) * 8;

    auto stage = [&](int kt, int buf) {
        const int k0 = kt * 32;
        {   // A-tile 128x32: 512 16B units, 1 per thread
            int u = tid;
            gld_lds16(A + (size_t)(bm + (u >> 2)) * kKp2 + k0 + ((u ^ (u >> 3)) & 3) * 8,
                      As + buf * 4096 + u * 8);
        }
#pragma unroll
        for (int p = 0; p < 3; p++) {   // B-tile 320x32: 1280 units
            int u = tid + p * 512;
            if (u < 1280)
                gld_lds16(BT + (size_t)(u >> 2) * kW2ld + k0 + ((u ^ (u >> 3)) & 3) * 8,
                          Bs + buf * 10240 + u * 8);
        }
    };

    f32x4 acc[2][10];
#pragma unroll
    for (int i = 0; i < 2; i++)
#pragma unroll
        for (int f = 0; f < 10; f++) acc[i][f] = (f32x4){0.f, 0.f, 0.f, 0.f};

    stage(0, 0);
    __syncthreads();

    for (int kt = 0; kt < kKp2 / 32; kt++) {
        const int cur = kt & 1;
        bf16x8 af0 = *reinterpret_cast<const bf16x8*>(
            &As[cur * 4096 + (wr * 32 + lq) * 32 + qs]);
        bf16x8 af1 = *reinterpret_cast<const bf16x8*>(
            &As[cur * 4096 + (wr * 32 + 16 + lq) * 32 + qs]);
        if (kt + 1 < kKp2 / 32) stage(kt + 1, cur ^ 1);
#pragma unroll
        for (int f = 0; f < 10; f++) {
            bf16x8 bfg = *reinterpret_cast<const bf16x8*>(
                &Bs[cur * 10240 + (wc * 160 + f * 16 + lq) * 32 + qs]);
            acc[0][f] = __builtin_amdgcn_mfma_f32_16x16x32_bf16(af0, bfg, acc[0][f], 0, 0, 0);
            acc[1][f] = __builtin_amdgcn_mfma_f32_16x16x32_bf16(af1, bfg, acc[1][f], 0, 0, 0);
        }
        __syncthreads();   // drains next-tile DMAs + guards buf reuse
    }

    // ---- fused LN2 epilogue: two 64-row halves through LDS (stride 328) ----
    float bv[10];
#pragma unroll
    for (int f = 0; f < 10; f++) {
        int col = wc * 160 + f * 16 + lq;
        bv[f] = (col < kD) ? b2[col] : 0.f;
    }
    const int team = tid >> 6;
#pragma unroll
    for (int h = 0; h < 2; h++) {
        if ((wr >> 1) == h) {
#pragma unroll
            for (int i = 0; i < 2; i++)
#pragma unroll
                for (int f = 0; f < 10; f++)
#pragma unroll
                    for (int r2 = 0; r2 < 4; r2++) {
                        int row = (wr & 1) * 32 + i * 16 + qd * 4 + r2;
                        int col = wc * 160 + f * 16 + lq;
                        smem[row * 328 + col] = f2bf(acc[i][f][r2] + bv[f]);
                    }
        }
        __syncthreads();
        for (int r = 0; r < 8; r++) {
            int rl = team * 8 + r;
            int n = bm + h * 64 + rl;
            size_t baseH = (size_t)n * kDp;
            float vals[5];
            float sum = 0.f;
#pragma unroll
            for (int i5 = 0; i5 < 5; i5++) {
                int idx = lane + i5 * 64;
                float t = 0.f;
                if (idx < kD) t = bu2f(hb[baseH + idx]) + bu2f(smem[rl * 328 + idx]);
                vals[i5] = t;
                sum += t;
            }
            for (int off2 = 1; off2 < 64; off2 <<= 1) sum += __shfl_xor(sum, off2, 64);
            float mean = sum / kD;
            float var = 0.f;
#pragma unroll
            for (int i5 = 0; i5 < 5; i5++) {
                int idx = lane + i5 * 64;
                if (idx < kD) { float dv = vals[i5] - mean; var += dv * dv; }
            }
            for (int off2 = 1; off2 < 64; off2 <<= 1) var += __shfl_xor(var, off2, 64);
            float rstd = rsqrtf(var / kD + 1e-5f);
#pragma unroll
            for (int i5 = 0; i5 < 5; i5++) {
                int idx = lane + i5 * 64;
                if (idx < kD)
                    hb[baseH + idx] = f2bf((vals[i5] - mean) * rstd * g[idx] + b[idx]);
            }
        }
        __syncthreads();
    }
}

// fp32 vector GEMM for the small head matmuls (M=2000)
__global__ __launch_bounds__(256) void gemm_kernel(
    const float* __restrict__ A, const float* __restrict__ W,
    const float* __restrict__ bias, float* __restrict__ C,
    int M, int N, int K, int relu)
{
    constexpr int BM = 64, BN = 64, BK = 16;
    __shared__ float As[BK][BM + 1];
    __shared__ float Bs[BK][BN + 1];
    const int bm = blockIdx.y * BM;
    const int bn = blockIdx.x * BN;
    const int tid = threadIdx.x;
    const int tr = tid / 16;
    const int tc = tid % 16;
    float acc[4][4] = {};
    for (int k0 = 0; k0 < K; k0 += BK) {
        for (int t = tid; t < BM * BK; t += 256) {
            int r = t / BK, c = t % BK;
            int gr = bm + r, gc = k0 + c;
            As[c][r] = (gr < M && gc < K) ? A[(size_t)gr * K + gc] : 0.f;
        }
        for (int t = tid; t < BK * BN; t += 256) {
            int r = t / BN, c = t % BN;
            int gr = k0 + r, gc = bn + c;
            Bs[r][c] = (gr < K && gc < N) ? W[(size_t)gr * N + gc] : 0.f;
        }
        __syncthreads();
#pragma unroll
        for (int k = 0; k < BK; k++) {
            float a[4], b[4];
#pragma unroll
            for (int i = 0; i < 4; i++) a[i] = As[k][tr * 4 + i];
#pragma unroll
            for (int j = 0; j < 4; j++) b[j] = Bs[k][tc * 4 + j];
#pragma unroll
            for (int i = 0; i < 4; i++)
#pragma unroll
                for (int j = 0; j < 4; j++) acc[i][j] += a[i] * b[j];
        }
        __syncthreads();
    }
#pragma unroll
    for (int i = 0; i < 4; i++) {
        int gr = bm + tr * 4 + i;
        if (gr >= M) continue;
#pragma unroll
        for (int j = 0; j < 4; j++) {
            int gc = bn + tc * 4 + j;
            if (gc >= N) continue;
            float v = acc[i][j];
            if (bias) v += bias[gc];
            if (relu) v = fmaxf(v, 0.f);
            C[(size_t)gr * N + gc] = v;
        }
    }
}

// ---------------------------------------------------------------------------
// node embed over full padded rows (pads written 0 -> no separate hb zero)
__global__ void node_embed_kernel(const int* __restrict__ x,
                                  const float* __restrict__ emb1,
                                  const float* __restrict__ emb2,
                                  ushort_t* __restrict__ hb)
{
    long long i = (long long)blockIdx.x * blockDim.x + threadIdx.x;
    if (i >= (long long)kN * kDp) return;
    int n = (int)(i / kDp), d = (int)(i % kDp);
    ushort_t v = 0;
    if (d < kD)
        v = f2bf(emb1[(size_t)x[n * 2] * kD + d] + emb2[(size_t)x[n * 2 + 1] * kD + d]);
    hb[i] = v;
}

__global__ void eftab_kernel(const float* __restrict__ emb_t, const float* __restrict__ emb_d,
                             const float* __restrict__ pw, const float* __restrict__ pb,
                             float* __restrict__ eftab)
{
    int tid = threadIdx.x;
    if (tid >= kT * kED) return;
    int t = tid / kED, j = tid % kED;
    int a0 = t / 3, a1 = t % 3;
    float acc = pb[j];
#pragma unroll
    for (int k = 0; k < kED; k++) {
        float s = emb_t[a0 * kED + k] + emb_d[a1 * kED + k];
        acc += s * pw[k * kED + j];
    }
    eftab[tid] = acc;
}

// all kL layers in one launch: blockIdx.x = layer
__global__ __launch_bounds__(256) void etaball_kernel(const float* __restrict__ eftab,
                                                      const float* __restrict__ ew5,
                                                      float* __restrict__ etab5)
{
    __shared__ float se[kT * kED];
    const int l = blockIdx.x;
    const float* ew = ew5 + (size_t)l * kED * kD;
    float* etab = etab5 + (size_t)l * kT * kD;
    for (int i = threadIdx.x; i < kT * kED; i += 256) se[i] = eftab[i];
    __syncthreads();
    for (int o = threadIdx.x; o < kT * kD; o += 256) {
        int t = o / kD, d = o % kD;
        float acc = 0.f;
#pragma unroll
        for (int k = 0; k < kED; k++) acc += se[t * kED + k] * ew[k * kD + d];
        etab[o] = acc;
    }
}

// EtabT2 rows for all layers: row j=t*4+h is etab[t] masked to head h.
__global__ void etabT2all_kernel(const float* __restrict__ etab5, ushort_t* __restrict__ wqv5)
{
    int i = blockIdx.x * 256 + threadIdx.x;
    if (i >= kL * 64 * kDp) return;
    int l = i / (64 * kDp);
    int r = i - l * (64 * kDp);
    int j = r / kDp, k = r % kDp;
    const float* etab = etab5 + (size_t)l * kT * kD;
    ushort_t v = 0;
    if (j < kT * kH && k < kD) {
        int t = j >> 2, hh = j & 3;
        if (k >= hh * kC && k < hh * kC + kC) v = f2bf(etab[t * kD + k]);
    }
    wqv5[(size_t)l * kQV * kDp + (size_t)kOffQE * kDp + r] = v;
}

// ---------------- CSR build (by dst) ----------------
__global__ void izero_kernel(int* __restrict__ p, int n)
{
    int i = blockIdx.x * 256 + threadIdx.x;
    if (i < n) p[i] = 0;
}

__global__ void deg_kernel(const int* __restrict__ dst, int* __restrict__ deg)
{
    int e = blockIdx.x * 256 + threadIdx.x;
    if (e >= kE) return;
    atomicAdd(&deg[dst[e]], 1);
}

__global__ __launch_bounds__(256) void scan1_kernel(const int* __restrict__ deg, int* __restrict__ bsum)
{
    __shared__ int s[256];
    int i = blockIdx.x * 256 + threadIdx.x;
    s[threadIdx.x] = (i < kN) ? deg[i] : 0;
    __syncthreads();
    for (int off = 128; off > 0; off >>= 1) {
        if (threadIdx.x < off) s[threadIdx.x] += s[threadIdx.x + off];
        __syncthreads();
    }
    if (threadIdx.x == 0) bsum[blockIdx.x] = s[0];
}

__global__ __launch_bounds__(256) void scan2_kernel(const int* __restrict__ bsum, int* __restrict__ boff,
                                                    int nb, int* __restrict__ row_ptr)
{
    __shared__ int s[256];
    int tid = threadIdx.x;
    int v = (tid < nb) ? bsum[tid] : 0;
    s[tid] = v;
    __syncthreads();
    for (int off = 1; off < 256; off <<= 1) {
        int t = (tid >= off) ? s[tid - off] : 0;
        __syncthreads();
        s[tid] += t;
        __syncthreads();
    }
    if (tid < nb) boff[tid] = s[tid] - v;
    if (tid == 255) row_ptr[kN] = s[255];
}

__global__ __launch_bounds__(256) void scan3_kernel(const int* __restrict__ deg, const int* __restrict__ boff,
                                                    int* __restrict__ row_ptr)
{
    __shared__ int s[256];
    int tid = threadIdx.x;
    int i = blockIdx.x * 256 + tid;
    int v = (i < kN) ? deg[i] : 0;
    s[tid] = v;
    __syncthreads();
    for (int off = 1; off < 256; off <<= 1) {
        int t = (tid >= off) ? s[tid - off] : 0;
        __syncthreads();
        s[tid] += t;
        __syncthreads();
    }
    if (i < kN) row_ptr[i] = boff[blockIdx.x] + s[tid] - v;
}

__global__ void poscopy_kernel(const int* __restrict__ row_ptr, int* __restrict__ pos)
{
    int i = blockIdx.x * 256 + threadIdx.x;
    if (i < kN) pos[i] = row_ptr[i];
}

__global__ void fill_kernel(const int* __restrict__ src, const int* __restrict__ dst,
                            const int* __restrict__ edge_attr,
                            int* __restrict__ pos, int* __restrict__ cpack)
{
    int e = blockIdx.x * 256 + threadIdx.x;
    if (e >= kE) return;
    int d = dst[e];
    int slot = atomicAdd(&pos[d], 1);
    cpack[slot] = (src[e] << 8) | (edge_attr[e * 2] * 3 + edge_attr[e * 2 + 1]);
}

// graph boundary pointers from sorted batch
__global__ void gptr_kernel(const int* __restrict__ batch, int* __restrict__ gptr)
{
    int i = blockIdx.x * 256 + threadIdx.x;
    if (i >= kN) return;
    int b1 = batch[i];
    int b0 = (i == 0) ? -1 : batch[i - 1];
    for (int g = b0 + 1; g <= b1; g++) gptr[g] = i;
    if (i == kN - 1)
        for (int g = b1 + 1; g <= kG; g++) gptr[g] = kN;
}

// ---------------------------------------------------------------------------
// Fused gather+score+LN1, head-group lane mapping. Round-6/9 proven form
// (measured 100 µs): r1 layout (stride 1280, scalar gather loads) + 2-edge
// unroll, V loads issued AFTER the shuffle reduce (r11's V-hoist regressed
// to 125 µs: vmcnt is issue-order counted, so hoisting forces the dot to
// drain the whole 20-load burst; trailing-V overlaps exp with V latency).
// ---------------------------------------------------------------------------
__global__ __launch_bounds__(256) void gsln_kernel(
    const int* __restrict__ row_ptr, const int* __restrict__ cpack,
    const ushort_t* __restrict__ qkvs,
    const float* __restrict__ etab,
    const float* __restrict__ g, const float* __restrict__ b,
    ushort_t* __restrict__ hb)
{
    __shared__ float sE[kT * kD];
    for (int i = threadIdx.x; i < kT * kD; i += 256) sE[i] = etab[i];
    __syncthreads();
    const int wslot = threadIdx.x >> 6, lane = threadIdx.x & 63;
    const int hh = lane >> 4, sub = lane & 15;
    const float scale = 0.11547005383792516f;

    int idxj[5];
    bool vj[5];
#pragma unroll
    for (int j = 0; j < 5; j++) {
        int o = sub + 16 * j;
        vj[j] = (o < kC);
        idxj[j] = hh * kC + (vj[j] ? o : 0);
    }

    for (int it = 0; it < 4; it++) {
        int n = blockIdx.x * 4 + wslot + it * 16000;
        int beg = row_ptr[n], end = row_ptr[n + 1];
        const ushort_t* qrow = qkvs + (size_t)n * kQV;

        float qv[5];
#pragma unroll
        for (int j = 0; j < 5; j++)
            qv[j] = vj[j] ? bu2f(qrow[idxj[j]]) : 0.f;

        float acc[5] = {0.f, 0.f, 0.f, 0.f, 0.f};
        float den = 0.f;
        for (int i = beg; i < end; i += 2) {
            int pk0 = cpack[i];
            bool h1 = (i + 1 < end);
            int pk1 = cpack[h1 ? i + 1 : i];
            int s0 = pk0 >> 8, t0 = pk0 & 255;
            int s1 = pk1 >> 8, t1 = pk1 & 255;
            const ushort_t* sr0 = qkvs + (size_t)s0 * kQV;
            const ushort_t* sr1 = qkvs + (size_t)s1 * kQV;

            // K loads for both edges (independent -> overlapped HBM latency)
            float k0v[5], k1v[5];
#pragma unroll
            for (int j = 0; j < 5; j++) {
                k0v[j] = vj[j] ? bu2f(sr0[kOffK + idxj[j]]) : 0.f;
                k1v[j] = vj[j] ? bu2f(sr1[kOffK + idxj[j]]) : 0.f;
            }
            float qe0 = bu2f(qrow[kOffQE + t0 * kH + hh]);
            float qe1 = bu2f(qrow[kOffQE + t1 * kH + hh]);

            float hp0 = 0.f, hp1 = 0.f;
#pragma unroll
            for (int j = 0; j < 5; j++) {
                hp0 += qv[j] * k0v[j];
                hp1 += qv[j] * k1v[j];
            }
            hp0 += __shfl_xor(hp0, 1, 64);  hp1 += __shfl_xor(hp1, 1, 64);
            hp0 += __shfl_xor(hp0, 2, 64);  hp1 += __shfl_xor(hp1, 2, 64);
            hp0 += __shfl_xor(hp0, 4, 64);  hp1 += __shfl_xor(hp1, 4, 64);
            hp0 += __shfl_xor(hp0, 8, 64);  hp1 += __shfl_xor(hp1, 8, 64);
            float a0 = fminf(fmaxf((hp0 + qe0) * scale, -60.f), 60.f);
            float a1 = fminf(fmaxf((hp1 + qe1) * scale, -60.f), 60.f);
            float eh0 = __expf(a0);
            float eh1 = h1 ? __expf(a1) : 0.f;
            den += eh0 + eh1;

            const float* ep0 = sE + t0 * kD;
            const float* ep1 = sE + t1 * kD;
#pragma unroll
            for (int j = 0; j < 5; j++) {
                if (vj[j]) {
                    float v0 = bu2f(sr0[kOffV + idxj[j]]) + ep0[idxj[j]];
                    float v1 = bu2f(sr1[kOffV + idxj[j]]) + ep1[idxj[j]];
                    acc[j] += eh0 * v0 + eh1 * v1;
                }
            }
        }

        const float inv_den = (den > 0.f) ? 1.f / den : 0.f;
        const ushort_t* skipp = qrow + kOffS;
        float vals[5], sum = 0.f;
#pragma unroll
        for (int j = 0; j < 5; j++) {
            float tV = 0.f;
            if (vj[j])
                tV = bu2f(hb[(size_t)n * kDp + idxj[j]]) + acc[j] * inv_den + bu2f(skipp[idxj[j]]);
            vals[j] = tV;
            sum += tV;
        }
        for (int off = 1; off < 64; off <<= 1) sum += __shfl_xor(sum, off, 64);
        float mean = sum / kD;
        float var = 0.f;
#pragma unroll
        for (int j = 0; j < 5; j++) {
            if (vj[j]) { float dv = vals[j] - mean; var += dv * dv; }
        }
        for (int off = 1; off < 64; off <<= 1) var += __shfl_xor(var, off, 64);
        float rstd = rsqrtf(var / kD + 1e-5f);
#pragma unroll
        for (int j = 0; j < 5; j++) {
            if (vj[j])
                hb[(size_t)n * kDp + idxj[j]] =
                    f2bf((vals[j] - mean) * rstd * g[idxj[j]] + b[idxj[j]]);
        }
    }
}

__global__ void zero_kernel(float* __restrict__ p, long long n)
{
    long long i = (long long)blockIdx.x * blockDim.x + threadIdx.x;
    if (i < n) p[i] = 0.f;
}

// mean-pool per graph (sorted batch -> segmented reduction, no atomics)
__global__ __launch_bounds__(256) void pool2_kernel(const ushort_t* __restrict__ hb,
                                                    const int* __restrict__ gptr,
                                                    float* __restrict__ pooled)
{
    int g = blockIdx.x;
    int beg = gptr[g], end = gptr[g + 1];
    float inv = (end > beg) ? 1.f / (float)(end - beg) : 0.f;
    for (int d = threadIdx.x; d < kD; d += 256) {
        float acc = 0.f;
        for (int n = beg; n < end; n++)
            acc += bu2f(hb[(size_t)n * kDp + d]);
        pooled[(size_t)g * kD + d] = acc * inv;
    }
}

// ---------------------------------------------------------------------------
extern "C" void kernel_launch(void* const* d_in, const int* in_sizes, int n_in,
                              void* d_out, int out_size, void* d_ws, size_t ws_size,
                              hipStream_t stream)
{
    const int* x          = (const int*)d_in[0];
    const int* edge_index = (const int*)d_in[1];
    const int* edge_attr  = (const int*)d_in[2];
    const int* batch      = (const int*)d_in[3];
    const int* src = edge_index;
    const int* dst = edge_index + kE;

    // ---- workspace layout (~221 MB; proven budget >= 266.8 MB) ----
    float* ws = (float*)d_ws;
    size_t off = 0;
    int* flag = (int*)(ws + off); off += 16;
    const bool big[33] = {false,false,false,false,false,false,false,false,false,false,
                          true, false, true, false, true, false, false, true, false, false,
                          false,false,false, true, false, true, false,false,false,false,
                          false,false,false};
    float* canonBase = ws + off;
    float* canon[33] = {};
    CvtTab tab;
    {
        int cnt = 0;
        long long cum = 0;
        for (int i = 4; i < 33; i++) {
            if (big[i]) continue;
            canon[i] = ws + off; off += (size_t)in_sizes[i];
            tab.src[cnt] = d_in[i];
            tab.off[cnt] = cum;
            cum += in_sizes[i];
            cnt++;
        }
        tab.off[cnt] = cum;   // cnt == 23
    }
    const long long cvtTotal = tab.off[23];
    off = (off + 3) & ~(size_t)3;
    int* deg     = (int*)(ws + off); off += (size_t)kN;
    int* row_ptr = (int*)(ws + off); off += (size_t)kN + 4;
    int* pos     = (int*)(ws + off); off += (size_t)kN;
    int* cpack   = (int*)(ws + off); off += (size_t)kE;
    int* bsum    = (int*)(ws + off); off += 256;
    int* boff    = (int*)(ws + off); off += 256;
    int* gptr    = (int*)(ws + off); off += (size_t)kG + 4;
    float* eftab = ws + off; off += (size_t)kT * kED;
    float* etab5 = ws + off; off += (size_t)kL * kT * kD;
    float* bqv5  = ws + off; off += (size_t)kL * kQV;
    off = (off + 3) & ~(size_t)3;
    ushort_t* hb   = (ushort_t*)(ws + off); off += (size_t)kN * kDp / 2;   // 41 MB
    ushort_t* QV   = (ushort_t*)(ws + off); off += (size_t)kN * kQV / 2;   // 164 MB (QKVS / FFN-mid)
    // per-layer transposed bf16 weights (arena pre-zeroed)
    ushort_t* warena = (ushort_t*)(ws + off);
    ushort_t* wqv5 = warena;                              // [kL][kQV][kDp]
    ushort_t* wt15 = wqv5 + (size_t)kL * kQV * kDp;       // [kL][kNpW1][kDp]
    ushort_t* wt25 = wt15 + (size_t)kL * kNpW1 * kDp;     // [kL][kNpW2][kW2ld]
    size_t warena_ushorts = (size_t)kL * (kQV + kNpW1) * kDp + (size_t)kL * kNpW2 * kW2ld;
    off += warena_ushorts / 2 + 4;
    // head temporaries alias QV (free after layer loop)
    float* pooled = (float*)QV;
    float* gbuf   = pooled + (size_t)kG * kD;
    float* t1     = gbuf + (size_t)kG * kFD;
    float* o2     = t1 + (size_t)kG * kFD;

    // ---- dtype detect + canonicalize all small tensors in ONE launch ----
    detect_kernel<<<1, 64, 0, stream>>>((const uint_t*)d_in[19], flag);
    cvtall_kernel<<<cdiv((int)cvtTotal, 256), 256, 0, stream>>>(tab, canonBase, cvtTotal, flag);

    auto mgemm = [&](const ushort_t* A, int lda, const ushort_t* BT, int ldb,
                     const float* bias, ushort_t* outB, int ldob,
                     int M, int N, int K, int relu) {
        dim3 grid(cdiv(N, gBN), M / gBM);
        mgemm_kernel<<<grid, 256, 0, stream>>>(A, lda, BT, ldb, bias, outB, ldob, M, N, K, relu);
    };
    auto gemm = [&](const float* A, const float* W, const float* bias, float* C,
                    int M, int N, int K, int relu) {
        dim3 grid(cdiv(N, 64), cdiv(M, 64));
        gemm_kernel<<<grid, 256, 0, stream>>>(A, W, bias, C, M, N, K, relu);
    };

    // ---- embeddings (full padded rows -> no separate hb zero) ----
    node_embed_kernel<<<cdiv((int)((long long)kN * kDp), 256), 256, 0, stream>>>(
        x, canon[4], canon[5], hb);
    eftab_kernel<<<1, 512, 0, stream>>>(canon[6], canon[7], canon[8], canon[9], eftab);

    // ---- CSR build + graph boundaries (once) ----
    const int nb = cdiv(kN, 256);   // 250
    izero_kernel<<<cdiv(kN, 256), 256, 0, stream>>>(deg, kN);
    deg_kernel<<<cdiv(kE, 256), 256, 0, stream>>>(dst, deg);
    scan1_kernel<<<nb, 256, 0, stream>>>(deg, bsum);
    scan2_kernel<<<1, 256, 0, stream>>>(bsum, boff, nb, row_ptr);
    scan3_kernel<<<nb, 256, 0, stream>>>(deg, boff, row_ptr);
    poscopy_kernel<<<cdiv(kN, 256), 256, 0, stream>>>(row_ptr, pos);
    fill_kernel<<<cdiv(kE, 256), 256, 0, stream>>>(src, dst, edge_attr, pos, cpack);
    gptr_kernel<<<cdiv(kN, 256), 256, 0, stream>>>(batch, gptr);

    // ---- weight prep: zero arena (pads must be 0), then batched fills ----
    zero_kernel<<<cdiv((int)(warena_ushorts / 2), 256) + 1, 256, 0, stream>>>(
        (float*)warena, (long long)(warena_ushorts / 2));
    {
        const long long sQV = (long long)kQV * kDp;
        const int g300 = cdiv(kL * kD * kD, 256);
        wtall_kernel<<<g300, 256, 0, stream>>>(d_in[10], wqv5, kD, kD, kDp, 0,     sQV, flag);
        wtall_kernel<<<g300, 256, 0, stream>>>(d_in[12], wqv5, kD, kD, kDp, kOffK, sQV, flag);
        wtall_kernel<<<g300, 256, 0, stream>>>(d_in[14], wqv5, kD, kD, kDp, kOffV, sQV, flag);
        wtall_kernel<<<g300, 256, 0, stream>>>(d_in[17], wqv5, kD, kD, kDp, kOffS, sQV, flag);
        wtall_kernel<<<cdiv(kL * kD * 1200, 256), 256, 0, stream>>>(
            d_in[23], wt15, kD, 1200, kDp, 0, (long long)kNpW1 * kDp, flag);
        wtall_kernel<<<cdiv(kL * 1200 * kD, 256), 256, 0, stream>>>(
            d_in[25], wt25, 1200, kD, kW2ld, 0, (long long)kNpW2 * kW2ld, flag);
    }
    etaball_kernel<<<kL, 256, 0, stream>>>(eftab, canon[16], etab5);
    etabT2all_kernel<<<cdiv(kL * 64 * kDp, 256), 256, 0, stream>>>(etab5, wqv5);
    biasqkvs_kernel<<<cdiv(kL * kQV, 256), 256, 0, stream>>>(
        canon[11], canon[13], canon[15], canon[18], bqv5);

    // ---- layers ----
    for (int l = 0; l < kL; l++) {
        const ushort_t* wqv = wqv5 + (size_t)l * kQV * kDp;
        const ushort_t* w1  = wt15 + (size_t)l * kNpW1 * kDp;
        const ushort_t* w2  = wt25 + (size_t)l * kNpW2 * kW2ld;
        const float* etab = etab5 + (size_t)l * kT * kD;

        // QKVS = hb @ [q|k|v|skip|qe]  (N=1264, stride 1280)
        mgemm(hb, kDp, wqv, kDp, bqv5 + (size_t)l * kQV, QV, kQV, kN, kQVn, kDp, 0);

        // fused gather+score+LN1 -> hb
        gsln_kernel<<<4000, 256, 0, stream>>>(row_ptr, cpack, QV, etab,
            canon[19] + (size_t)l * kD, canon[20] + (size_t)l * kD, hb);

        // FFN1 (proven mgemm): mid (bf16 [64000][1216]) in QV
        ushort_t* mid = QV;
        mgemm(hb, kDp, w1, kDp, canon[24] + (size_t)l * 1200, mid, kKp2,
              kN, 1200, kDp, 1);

        // fused FFN2+LN2: hb = LN(hb + mid @ w2T + b2); f never hits HBM
        ffn2ln_kernel<<<kN / 128, 512, 0, stream>>>(mid, w2,
            canon[26] + (size_t)l * kD, hb,
            canon[21] + (size_t)l * kD, canon[22] + (size_t)l * kD);
    }

    // ---- pooling + heads (QV free) ----
    pool2_kernel<<<kG, 256, 0, stream>>>(hb, gptr, pooled);

    gemm(pooled, canon[27], canon[28], gbuf, kG, kFD, kD, 0);
    gemm(gbuf, canon[29], canon[30], t1, kG, kFD, kFD, 1);
    gemm(t1, canon[31], canon[32], o2, kG, kFD / 2, kFD, 0);

    out_write_kernel<<<cdiv(kG * kFD, 256), 256, 0, stream>>>(
        gbuf, d_out, (long long)kG * kFD, 0, flag);
    out_write_kernel<<<cdiv(kG * kFD / 2, 256), 256, 0, stream>>>(
        o2, d_out, (long long)kG * (kFD / 2), (long long)kG * kFD, flag);
}